// Round 9
// baseline (399.901 us; speedup 1.0000x reference)
//
#include <hip/hip_runtime.h>
#include <hip/hip_bf16.h>
#include <math.h>

#define B_SZ 128
#define N_OTH 2048
#define F_IMG 1024
#define F_TXT 512
#define D_EMB 512

typedef __attribute__((ext_vector_type(8))) short short8;    // 8 bf16 (4 VGPR)
typedef __attribute__((ext_vector_type(16))) float f32x16;   // 32x32 MFMA acc

static __device__ __forceinline__ ushort f2bf(float f) {
    __hip_bfloat16 h = __float2bfloat16(f);   // HW RNE convert
    return *reinterpret_cast<ushort*>(&h);
}

// ---------------- fused: encoders (blocks 0..127) + W-prep (blocks 128..191) ----------------
__global__ __launch_bounds__(512) void k_prep(const float* __restrict__ in_img,
                                              const float* __restrict__ in_txt,
                                              const float* __restrict__ W_img,
                                              const float* __restrict__ W_txt,
                                              const float* __restrict__ p_ls,
                                              float* __restrict__ img,
                                              float* __restrict__ logit_in,
                                              ushort* __restrict__ wf) {
    if (blockIdx.x >= B_SZ) {
        // ---- W_txt -> bf16 MFMA B-fragment repack ----
        // frag = kstep(0..31)*16 + ct(0..15); lane l: col ct*32+(l&31), k = kstep*16+(l>>5)*8+j
        const int g = (blockIdx.x - B_SZ) * 512 + threadIdx.x;   // 32768 total
        const int l = g & 63;
        const int frag = g >> 6;
        const int kstep = frag >> 4;
        const int ct = frag & 15;
        const int col = ct * 32 + (l & 31);
        const int kb = kstep * 16 + (l >> 5) * 8;
        short8 o;
#pragma unroll
        for (int j = 0; j < 8; ++j) o[j] = (short)f2bf(W_txt[(kb + j) * D_EMB + col]);
        *(short8*)(wf + (size_t)g * 8) = o;
        return;
    }
    const int b = blockIdx.x;
    const int d = threadIdx.x;
    __shared__ float row[F_IMG];
    __shared__ float wsum[8];
    __shared__ float s_rn;
    const int lane = d & 63, wv = d >> 6;

    // ---- image ----
    for (int i = d; i < F_IMG; i += 512) row[i] = in_img[b * F_IMG + i];
    __syncthreads();
    float acc = 0.f;
#pragma unroll 8
    for (int f = 0; f < F_IMG; ++f) acc = fmaf(row[f], W_img[f * D_EMB + d], acc);
    float sq = acc * acc;
#pragma unroll
    for (int off = 32; off > 0; off >>= 1) sq += __shfl_down(sq, off);
    if (lane == 0) wsum[wv] = sq;
    __syncthreads();
    if (d == 0) {
        float s = 0.f;
        for (int w = 0; w < 8; ++w) s += wsum[w];
        s_rn = 1.0f / sqrtf(s);
    }
    __syncthreads();
    const float iv = acc * s_rn;
    img[b * D_EMB + d] = iv;

    // ---- text ----
    __syncthreads();
    row[d] = in_txt[b * F_TXT + d];
    __syncthreads();
    float tacc = 0.f;
#pragma unroll 8
    for (int f = 0; f < F_TXT; ++f) tacc = fmaf(row[f], W_txt[f * D_EMB + d], tacc);
    float tsq = tacc * tacc;
#pragma unroll
    for (int off = 32; off > 0; off >>= 1) tsq += __shfl_down(tsq, off);
    __syncthreads();
    if (lane == 0) wsum[wv] = tsq;
    __syncthreads();
    if (d == 0) {
        float s = 0.f;
        for (int w = 0; w < 8; ++w) s += wsum[w];
        s_rn = 1.0f / sqrtf(s);
    }
    __syncthreads();
    float pd = (tacc * s_rn) * iv;
#pragma unroll
    for (int off = 32; off > 0; off >>= 1) pd += __shfl_down(pd, off);
    __syncthreads();
    if (lane == 0) wsum[wv] = pd;
    __syncthreads();
    if (d == 0) {
        float s = 0.f;
        for (int w = 0; w < 8; ++w) s += wsum[w];
        logit_in[b] = expf(p_ls[0]) * s;
    }
}

// ---------------- fused GEMM + num/den reduction ----------------
// Block: 512 thr = 8 waves. BM=128 rows, BN=512 cols, BK=64, K=512 (8 tiles).
// Wave wv: all 128 rows x cols [wv*64, wv*64+64). acc = 4m x 2n x f32x16 = 128 VGPR.
// Full-tile-ahead register prefetch of BOTH operands:
//   per tile: {issue A(t+1)} -> {MFMA on resident bfr, zero vmem waits}
//             -> {issue B(t+1)} -> {cvt+ds_write A(t+1), slack ~2000cyc}
//             -> lgkm-only barrier (B(t+1) stays in flight across it).
__device__ __forceinline__ void loadA(const float* gs, float4 v[4]) {
    v[0] = *(const float4*)(gs + 0);
    v[1] = *(const float4*)(gs + 4);
    v[2] = *(const float4*)(gs + 8);
    v[3] = *(const float4*)(gs + 12);
}
__device__ __forceinline__ void cvtWrite(char* buf, int wb0, int wb1, const float4 v[4]) {
    short8 p0, p1;
    p0[0] = (short)f2bf(v[0].x); p0[1] = (short)f2bf(v[0].y); p0[2] = (short)f2bf(v[0].z); p0[3] = (short)f2bf(v[0].w);
    p0[4] = (short)f2bf(v[1].x); p0[5] = (short)f2bf(v[1].y); p0[6] = (short)f2bf(v[1].z); p0[7] = (short)f2bf(v[1].w);
    p1[0] = (short)f2bf(v[2].x); p1[1] = (short)f2bf(v[2].y); p1[2] = (short)f2bf(v[2].z); p1[3] = (short)f2bf(v[2].w);
    p1[4] = (short)f2bf(v[3].x); p1[5] = (short)f2bf(v[3].y); p1[6] = (short)f2bf(v[3].z); p1[7] = (short)f2bf(v[3].w);
    *(short8*)(buf + wb0) = p0;
    *(short8*)(buf + wb1) = p1;
}

__global__ __launch_bounds__(512, 2) void k_gemm(const float* __restrict__ oth,
                                                 const ushort* __restrict__ wf,
                                                 const float* __restrict__ img,
                                                 float* __restrict__ numA,
                                                 float* __restrict__ denA) {
    __shared__ ushort sA[2][128 * 64];   // 2 x 16 KB bf16, swizzled
    __shared__ float redN[8][128];
    __shared__ float redD[8][128];
    const int tid = threadIdx.x;
    const int l = tid & 63;
    const int wv = tid >> 6;
    const int b = blockIdx.x >> 4;                 // 16 blocks per batch element
    const size_t row0 = (size_t)blockIdx.x * 128;

    // staging map: thread -> 1 row, 16 consecutive k (64 B global, 32 B LDS)
    const int srow = tid >> 2;           // 0..127
    const int sk0 = (tid & 3) * 16;
    const float* gsrc = oth + (row0 + srow) * F_TXT + sk0;
    const int swz = (srow & 7) << 4;
    const int wb0 = srow * 128 + ((sk0 * 2 + 0) ^ swz);
    const int wb1 = srow * 128 + ((sk0 * 2 + 16) ^ swz);

    // A-read: row r = m*32 + (l&31); byte = r*128 + ((ks*32+(l>>5)*16) ^ ((l&7)<<4))
    int rowbase[4];
#pragma unroll
    for (int m = 0; m < 4; ++m) rowbase[m] = (m * 32 + (l & 31)) * 128;
    int koff[4];
#pragma unroll
    for (int ks = 0; ks < 4; ++ks) koff[ks] = ((ks * 32 + (l >> 5) * 16) ^ ((l & 7) << 4));

    f32x16 acc[4][2];
#pragma unroll
    for (int m = 0; m < 4; ++m)
#pragma unroll
        for (int n = 0; n < 2; ++n)
#pragma unroll
            for (int r = 0; r < 16; ++r) acc[m][n][r] = 0.f;

    float4 va[4];
    short8 bfr[4][2];

    // prologue: A(0) -> LDS, B(0) -> regs
    loadA(gsrc, va);
#pragma unroll
    for (int ks = 0; ks < 4; ++ks)
#pragma unroll
        for (int n = 0; n < 2; ++n)
            bfr[ks][n] = *(const short8*)(wf + ((size_t)(ks * 16 + wv * 2 + n) * 64 + l) * 8);
    cvtWrite((char*)sA[0], wb0, wb1, va);
    __syncthreads();

#pragma unroll
    for (int t = 0; t < 8; ++t) {
        const int cur = t & 1;
        // S1: issue HBM A-prefetch for tile t+1 (oldest in queue; consumed at S4)
        if (t < 7) loadA(gsrc + (t + 1) * 64, va);
        __builtin_amdgcn_sched_barrier(0);
        // S2: MFMA cluster on resident registers — no VMEM waits on the critical path
        __builtin_amdgcn_s_setprio(1);
#pragma unroll
        for (int ks = 0; ks < 4; ++ks) {
            short8 af[4];
#pragma unroll
            for (int m = 0; m < 4; ++m)
                af[m] = *(const short8*)((const char*)sA[cur] + rowbase[m] + koff[ks]);
#pragma unroll
            for (int m = 0; m < 4; ++m)
#pragma unroll
                for (int n = 0; n < 2; ++n)
                    acc[m][n] = __builtin_amdgcn_mfma_f32_32x32x16_bf16(af[m], bfr[ks][n], acc[m][n], 0, 0, 0);
        }
        __builtin_amdgcn_s_setprio(0);
        __builtin_amdgcn_sched_barrier(0);
        if (t < 7) {
            // S3: issue B(t+1) L2 loads (land under S4 + barrier + next tile's ds_reads)
#pragma unroll
            for (int ks = 0; ks < 4; ++ks)
#pragma unroll
                for (int n = 0; n < 2; ++n)
                    bfr[ks][n] = *(const short8*)(wf + ((size_t)((t + 1) * 64 + ks * 16 + wv * 2 + n) * 64 + l) * 8);
            __builtin_amdgcn_sched_barrier(0);
            // S4: cvt+stage A(t+1); its wait (vmcnt leaves B in flight) has ~full-tile slack
            cvtWrite((char*)sA[cur ^ 1], wb0, wb1, va);
            // S5: lgkm-only barrier; B(t+1) global loads stay in flight across it
            asm volatile("s_waitcnt lgkmcnt(0)" ::: "memory");
            __builtin_amdgcn_sched_barrier(0);
            __builtin_amdgcn_s_barrier();
            __builtin_amdgcn_sched_barrier(0);
        }
    }

    // epilogue: per-row num = sum_c P*img[c], den = sum_c P^2
    const float ic0 = img[b * D_EMB + wv * 64 + (l & 31)];
    const float ic1 = img[b * D_EMB + wv * 64 + 32 + (l & 31)];
#pragma unroll
    for (int m = 0; m < 4; ++m) {
#pragma unroll
        for (int rg = 0; rg < 16; ++rg) {
            const float p = acc[m][0][rg];
            const float q = acc[m][1][rg];
            float tn = p * ic0 + q * ic1;
            float td = p * p + q * q;
#pragma unroll
            for (int off = 1; off <= 16; off <<= 1) {
                tn += __shfl_xor(tn, off);
                td += __shfl_xor(td, off);
            }
            if ((l & 31) == 0) {
                const int r = m * 32 + (rg & 3) + 8 * (rg >> 2) + 4 * (l >> 5);
                redN[wv][r] = tn;
                redD[wv][r] = td;
            }
        }
    }
    __syncthreads();
    if (tid < 128) {
        float tn = 0.f, td = 0.f;
#pragma unroll
        for (int w = 0; w < 8; ++w) { tn += redN[w][tid]; td += redD[w][tid]; }
        numA[row0 + tid] = tn;
        denA[row0 + tid] = td;
    }
}

// ---------------- logits + full bitonic sort + output assembly ----------------
__global__ __launch_bounds__(512) void k_topk(const float* __restrict__ numA,
                                              const float* __restrict__ denA,
                                              const float* __restrict__ logit_in,
                                              const float* __restrict__ p_ls,
                                              float* __restrict__ out) {
    const int b = blockIdx.x;
    const int tid = threadIdx.x;
    const float scale = expf(p_ls[0]);
    __shared__ float a[N_OTH];
    for (int i = tid; i < N_OTH; i += 512) {
        const float nu = numA[(size_t)b * N_OTH + i];
        const float de = denA[(size_t)b * N_OTH + i];
        a[i] = scale * nu / sqrtf(de);
    }
    __syncthreads();
    for (unsigned k = 2; k <= N_OTH; k <<= 1) {
        for (unsigned j = k >> 1; j > 0; j >>= 1) {
#pragma unroll
            for (int s = 0; s < N_OTH / 512; ++s) {
                const unsigned i = tid + s * 512u;
                const unsigned ixj = i ^ j;
                if (ixj > i) {
                    const bool asc = ((i & k) == 0);
                    const float x = a[i], y = a[ixj];
                    if ((x > y) == asc) { a[i] = y; a[ixj] = x; }
                }
            }
            __syncthreads();
        }
    }
    if (tid < 128) {
        const int j = tid;
        float v;
        if (j == b) {
            v = logit_in[b];
        } else {
            const int m = j - (j > b ? 1 : 0);
            v = a[N_OTH - 1 - m];
        }
        out[b * 128 + j] = v;
    }
}

extern "C" void kernel_launch(void* const* d_in, const int* in_sizes, int n_in,
                              void* d_out, int out_size, void* d_ws, size_t ws_size,
                              hipStream_t stream) {
    const float* in_img = (const float*)d_in[0];
    const float* in_txt = (const float*)d_in[1];
    const float* oth    = (const float*)d_in[2];
    const float* W_img  = (const float*)d_in[3];
    const float* W_txt  = (const float*)d_in[4];
    const float* p_ls   = (const float*)d_in[5];
    float* out = (float*)d_out;

    float* ws = (float*)d_ws;
    float* img      = ws;                                  // 65536 floats
    float* logit_in = ws + 65536;                          // 128
    float* numA     = ws + 65536 + 128;                    // 262144
    float* denA     = numA + 262144;                       // 262144
    ushort* wfrag   = (ushort*)(denA + 262144);            // 262144 ushorts (512 KB)

    k_prep<<<B_SZ + 64, 512, 0, stream>>>(in_img, in_txt, W_img, W_txt, p_ls, img, logit_in, wfrag);
    k_gemm<<<(B_SZ * N_OTH) / 128, 512, 0, stream>>>(oth, wfrag, img, numA, denA);
    k_topk<<<B_SZ, 512, 0, stream>>>(numA, denA, logit_in, p_ls, out);
}

// Round 10
// 391.320 us; speedup vs baseline: 1.0219x; 1.0219x over previous
//
#include <hip/hip_runtime.h>
#include <hip/hip_bf16.h>
#include <math.h>

#define B_SZ 128
#define N_OTH 2048
#define F_IMG 1024
#define F_TXT 512
#define D_EMB 512
#define TOT (B_SZ * N_OTH)

typedef __attribute__((ext_vector_type(8))) short short8;    // 8 bf16 (4 VGPR)
typedef __attribute__((ext_vector_type(16))) float f32x16;   // 32x32 MFMA acc

static __device__ __forceinline__ ushort f2bf(float f) {
    __hip_bfloat16 h = __float2bfloat16(f);   // HW RNE convert
    return *reinterpret_cast<ushort*>(&h);
}

static __device__ __forceinline__ void glds16(const float* g, float* l) {
    __builtin_amdgcn_global_load_lds((const __attribute__((address_space(1))) void*)g,
                                     (__attribute__((address_space(3))) void*)l, 16, 0, 0);
}

// ---------------- fused: encoders (blocks 0..127) + W-prep (blocks 128..191) ----------------
__global__ __launch_bounds__(512) void k_prep(const float* __restrict__ in_img,
                                              const float* __restrict__ in_txt,
                                              const float* __restrict__ W_img,
                                              const float* __restrict__ W_txt,
                                              const float* __restrict__ p_ls,
                                              float* __restrict__ img,
                                              float* __restrict__ logit_in,
                                              ushort* __restrict__ wf) {
    if (blockIdx.x >= B_SZ) {
        // W_txt -> bf16 MFMA B-fragment repack:
        // frag = kstep(0..31)*16 + ct(0..15); lane l: col ct*32+(l&31), k = kstep*16+(l>>5)*8+j
        const int g = (blockIdx.x - B_SZ) * 512 + threadIdx.x;   // 32768 total
        const int l = g & 63;
        const int frag = g >> 6;
        const int kstep = frag >> 4;
        const int ct = frag & 15;
        const int col = ct * 32 + (l & 31);
        const int kb = kstep * 16 + (l >> 5) * 8;
        short8 o;
#pragma unroll
        for (int j = 0; j < 8; ++j) o[j] = (short)f2bf(W_txt[(kb + j) * D_EMB + col]);
        *(short8*)(wf + (size_t)g * 8) = o;
        return;
    }
    const int b = blockIdx.x;
    const int d = threadIdx.x;
    __shared__ float row[F_IMG];
    __shared__ float wsum[8];
    __shared__ float s_rn;
    const int lane = d & 63, wv = d >> 6;

    for (int i = d; i < F_IMG; i += 512) row[i] = in_img[b * F_IMG + i];
    __syncthreads();
    float acc = 0.f;
#pragma unroll 8
    for (int f = 0; f < F_IMG; ++f) acc = fmaf(row[f], W_img[f * D_EMB + d], acc);
    float sq = acc * acc;
#pragma unroll
    for (int off = 32; off > 0; off >>= 1) sq += __shfl_down(sq, off);
    if (lane == 0) wsum[wv] = sq;
    __syncthreads();
    if (d == 0) {
        float s = 0.f;
        for (int w = 0; w < 8; ++w) s += wsum[w];
        s_rn = 1.0f / sqrtf(s);
    }
    __syncthreads();
    const float iv = acc * s_rn;
    img[b * D_EMB + d] = iv;

    __syncthreads();
    row[d] = in_txt[b * F_TXT + d];
    __syncthreads();
    float tacc = 0.f;
#pragma unroll 8
    for (int f = 0; f < F_TXT; ++f) tacc = fmaf(row[f], W_txt[f * D_EMB + d], tacc);
    float tsq = tacc * tacc;
#pragma unroll
    for (int off = 32; off > 0; off >>= 1) tsq += __shfl_down(tsq, off);
    __syncthreads();
    if (lane == 0) wsum[wv] = tsq;
    __syncthreads();
    if (d == 0) {
        float s = 0.f;
        for (int w = 0; w < 8; ++w) s += wsum[w];
        s_rn = 1.0f / sqrtf(s);
    }
    __syncthreads();
    float pd = (tacc * s_rn) * iv;
#pragma unroll
    for (int off = 32; off > 0; off >>= 1) pd += __shfl_down(pd, off);
    __syncthreads();
    if (lane == 0) wsum[wv] = pd;
    __syncthreads();
    if (d == 0) {
        float s = 0.f;
        for (int w = 0; w < 8; ++w) s += wsum[w];
        logit_in[b] = expf(p_ls[0]) * s;
    }
}

// ---------------- fused GEMM + num/den partial reduction ----------------
// Block: 256 thr = 4 waves. 64 rows x 256 cols (half h of N=512). BK=64, 8 tiles.
// Wave wv: 64 rows x cols [h*256 + wv*64, +64). acc = 2m x 2n x f32x16 = 64 VGPR.
// A: fp32 in LDS via global_load_lds, 3 buffers, staged 2 tiles ahead.
//   Source-side swizzle: LDS[row][g] = global[row][g ^ (row&7)] (16B granules);
//   read applies the same XOR. bf16 convert at fragment-read time.
// Raw s_barrier + lgkmcnt(0) only: glds(t+2) crosses barriers; in-order vmcnt
//   guarantees glds(t) complete once B(t) (issued later) is consumed.
__global__ __launch_bounds__(256, 3) void k_gemm(const float* __restrict__ oth,
                                                 const ushort* __restrict__ wf,
                                                 const float* __restrict__ img,
                                                 float* __restrict__ numA,    // [2][TOT]
                                                 float* __restrict__ denA) {  // [2][TOT]
    __shared__ float sA[3][64 * 64];   // 3 x 16 KB fp32
    __shared__ float redN[4][64];
    __shared__ float redD[4][64];
    const int tid = threadIdx.x;
    const int l = tid & 63;
    const int wv = tid >> 6;
    const int strip = blockIdx.x >> 1;
    const int h = blockIdx.x & 1;
    const int b = strip >> 5;                       // 32 strips per batch element
    const size_t row0 = (size_t)strip * 64;

    // staging source addrs: instr j covers rows wv*16+j*4 .. +3
    const float* gA[4];
#pragma unroll
    for (int j = 0; j < 4; ++j) {
        const int row = wv * 16 + j * 4 + (l >> 4);
        const int gcol = (l & 15) ^ (row & 7);
        gA[j] = oth + (row0 + row) * F_TXT + gcol * 4;
    }

    // B fragments: ct = h*8 + wv*2 + n; frag = kstep*16 + ct; addr = (frag*64+l)*8
    const ushort* wbase = wf + ((size_t)(h * 8 + wv * 2) * 64 + l) * 8;

    f32x16 acc[2][2];
#pragma unroll
    for (int m = 0; m < 2; ++m)
#pragma unroll
        for (int n = 0; n < 2; ++n)
#pragma unroll
            for (int r = 0; r < 16; ++r) acc[m][n][r] = 0.f;

    // prologue: stage tiles 0 and 1
#pragma unroll
    for (int j = 0; j < 4; ++j) glds16(gA[j] + 0 * 64, &sA[0][(wv * 16 + j * 4) * 64]);
#pragma unroll
    for (int j = 0; j < 4; ++j) glds16(gA[j] + 1 * 64, &sA[1][(wv * 16 + j * 4) * 64]);
    __builtin_amdgcn_sched_barrier(0);
    asm volatile("s_waitcnt vmcnt(4)" ::: "memory");   // tile0 landed; tile1 in flight
    __builtin_amdgcn_sched_barrier(0);
    __builtin_amdgcn_s_barrier();
    __builtin_amdgcn_sched_barrier(0);

#pragma unroll
    for (int t = 0; t < 8; ++t) {
        const int cur = t % 3;
        // S1: B for tile t (L2-resident); consuming these forces glds(<=t+1) complete
        short8 bfr[4][2];
#pragma unroll
        for (int ks = 0; ks < 4; ++ks)
#pragma unroll
            for (int n = 0; n < 2; ++n)
                bfr[ks][n] = *(const short8*)(wbase + (size_t)((t * 4 + ks) * 16 + n) * 512);
        __builtin_amdgcn_sched_barrier(0);
        // S2: stage tile t+2 (HBM -> LDS, no VGPR round-trip); crosses barriers
        if (t < 6) {
#pragma unroll
            for (int j = 0; j < 4; ++j)
                glds16(gA[j] + (t + 2) * 64, &sA[(t + 2) % 3][(wv * 16 + j * 4) * 64]);
        }
        __builtin_amdgcn_sched_barrier(0);
        // S3: compute tile t: fp32 ds_read + cvt + MFMA
        __builtin_amdgcn_s_setprio(1);
#pragma unroll
        for (int ks = 0; ks < 4; ++ks) {
            short8 af[2];
#pragma unroll
            for (int m = 0; m < 2; ++m) {
                const int r = m * 32 + (l & 31);
                const int g0 = ks * 4 + (l >> 5) * 2;
                const float4 fa = *(const float4*)&sA[cur][r * 64 + ((g0 ^ (r & 7)) << 2)];
                const float4 fb = *(const float4*)&sA[cur][r * 64 + (((g0 + 1) ^ (r & 7)) << 2)];
                short8 v;
                v[0] = (short)f2bf(fa.x); v[1] = (short)f2bf(fa.y);
                v[2] = (short)f2bf(fa.z); v[3] = (short)f2bf(fa.w);
                v[4] = (short)f2bf(fb.x); v[5] = (short)f2bf(fb.y);
                v[6] = (short)f2bf(fb.z); v[7] = (short)f2bf(fb.w);
                af[m] = v;
            }
#pragma unroll
            for (int m = 0; m < 2; ++m)
#pragma unroll
                for (int n = 0; n < 2; ++n)
                    acc[m][n] = __builtin_amdgcn_mfma_f32_32x32x16_bf16(af[m], bfr[ks][n], acc[m][n], 0, 0, 0);
        }
        __builtin_amdgcn_s_setprio(0);
        // S4: raw barrier, LDS-drain only (in-flight glds stays outstanding)
        if (t < 7) {
            asm volatile("s_waitcnt lgkmcnt(0)" ::: "memory");
            __builtin_amdgcn_sched_barrier(0);
            __builtin_amdgcn_s_barrier();
            __builtin_amdgcn_sched_barrier(0);
        }
    }

    // epilogue: per-row partials num = sum_c P*img[c], den = sum_c P^2 (this half)
    float ic[2];
#pragma unroll
    for (int n = 0; n < 2; ++n)
        ic[n] = img[b * D_EMB + h * 256 + wv * 64 + n * 32 + (l & 31)];
#pragma unroll
    for (int m = 0; m < 2; ++m) {
#pragma unroll
        for (int rg = 0; rg < 16; ++rg) {
            const float p = acc[m][0][rg];
            const float q = acc[m][1][rg];
            float tn = p * ic[0] + q * ic[1];
            float td = p * p + q * q;
#pragma unroll
            for (int off = 1; off <= 16; off <<= 1) {
                tn += __shfl_xor(tn, off);
                td += __shfl_xor(td, off);
            }
            if ((l & 31) == 0) {
                const int r = m * 32 + (rg & 3) + 8 * (rg >> 2) + 4 * (l >> 5);
                redN[wv][r] = tn;
                redD[wv][r] = td;
            }
        }
    }
    __syncthreads();
    if (tid < 64) {
        float tn = 0.f, td = 0.f;
#pragma unroll
        for (int w = 0; w < 4; ++w) { tn += redN[w][tid]; td += redD[w][tid]; }
        numA[(size_t)h * TOT + row0 + tid] = tn;
        denA[(size_t)h * TOT + row0 + tid] = td;
    }
}

// ---------------- logits + full bitonic sort + output assembly ----------------
__global__ __launch_bounds__(512) void k_topk(const float* __restrict__ numA,
                                              const float* __restrict__ denA,
                                              const float* __restrict__ logit_in,
                                              const float* __restrict__ p_ls,
                                              float* __restrict__ out) {
    const int b = blockIdx.x;
    const int tid = threadIdx.x;
    const float scale = expf(p_ls[0]);
    __shared__ float a[N_OTH];
    for (int i = tid; i < N_OTH; i += 512) {
        const size_t idx = (size_t)b * N_OTH + i;
        const float nu = numA[idx] + numA[TOT + idx];
        const float de = denA[idx] + denA[TOT + idx];
        a[i] = scale * nu / sqrtf(de);
    }
    __syncthreads();
    for (unsigned k = 2; k <= N_OTH; k <<= 1) {
        for (unsigned j = k >> 1; j > 0; j >>= 1) {
#pragma unroll
            for (int s = 0; s < N_OTH / 512; ++s) {
                const unsigned i = tid + s * 512u;
                const unsigned ixj = i ^ j;
                if (ixj > i) {
                    const bool asc = ((i & k) == 0);
                    const float x = a[i], y = a[ixj];
                    if ((x > y) == asc) { a[i] = y; a[ixj] = x; }
                }
            }
            __syncthreads();
        }
    }
    if (tid < 128) {
        const int j = tid;
        float v;
        if (j == b) {
            v = logit_in[b];
        } else {
            const int m = j - (j > b ? 1 : 0);
            v = a[N_OTH - 1 - m];
        }
        out[b * 128 + j] = v;
    }
}

extern "C" void kernel_launch(void* const* d_in, const int* in_sizes, int n_in,
                              void* d_out, int out_size, void* d_ws, size_t ws_size,
                              hipStream_t stream) {
    const float* in_img = (const float*)d_in[0];
    const float* in_txt = (const float*)d_in[1];
    const float* oth    = (const float*)d_in[2];
    const float* W_img  = (const float*)d_in[3];
    const float* W_txt  = (const float*)d_in[4];
    const float* p_ls   = (const float*)d_in[5];
    float* out = (float*)d_out;

    float* ws = (float*)d_ws;
    float* img      = ws;                                   // 65536
    float* logit_in = ws + 65536;                           // 128
    float* numA     = ws + 65536 + 128;                     // 2*TOT
    float* denA     = numA + 2 * TOT;                       // 2*TOT
    ushort* wfrag   = (ushort*)(denA + 2 * TOT);            // 262144 ushorts

    k_prep<<<B_SZ + 64, 512, 0, stream>>>(in_img, in_txt, W_img, W_txt, p_ls, img, logit_in, wfrag);
    k_gemm<<<(TOT / 64) * 2, 256, 0, stream>>>(oth, wfrag, img, numA, denA);
    k_topk<<<B_SZ, 512, 0, stream>>>(numA, denA, logit_in, p_ls, out);
}